// Round 3
// baseline (236.212 us; speedup 1.0000x reference)
//
#include <hip/hip_runtime.h>

// LocalSelfAttention2d fused MFMA implementation for gfx950.
// B=4, CIN=HC=256, heads=8, dh=32, P=8, img 128x128, pad 4/4 -> 136x136, 17x17 windows.
//
// R3: 1024-thread blocks (16 waves, 2 waves/head) for 4 waves/SIMD occupancy.
// K0: convert w_qkv (768x256) and w_out (256x256) fp32 -> bf16 into d_ws.
// K1 (fused, block = (b,win)):
//   phase0: stage x window-tile as bf16 in LDS xs[64 pos][264 ch-stride]
//   phase1: QKV GEMM via mfma_f32_16x16x32_bf16 (wave = head x pos-half) -> per-head LDS q/k/vT
//   phase2: attention (wave = head x query-half): S=mfma(K,Q), in-reg softmax,
//           P via head LDS, O^T=mfma(vT,P), normalize, o -> LDS os (overlays xs)
//   phase3: out-proj GEMM (wave = 16 out channels) + bias + crop -> y

typedef __attribute__((ext_vector_type(8))) short bf16x8;
typedef __attribute__((ext_vector_type(4))) float f32x4;

#define CIN   256
#define NWROW 17
#define NWIN  289
#define PADO  4
#define HIMG  128
#define ATT_SCALE 0.17677669529663687f  // 1/sqrt(32)

// LDS geometry (ushort units)
#define XS_STRIDE 264                       // 528 B rows: 16B aligned, 2-way max on frag reads
#define XS_SIZE   (64 * XS_STRIDE)          // 16896
#define QK_STRIDE 40                        // 80 B rows (16B aligned)
#define VT_STRIDE 72                        // 144 B rows (16B aligned)
#define P_STRIDE  72
#define WREG_Q    0
#define WREG_K    (64 * QK_STRIDE)          // 2560
#define WREG_VT   (2 * 64 * QK_STRIDE)      // 5120  (P overlays [0..4608) < 5120)
#define WREG_SIZE (WREG_VT + 32 * VT_STRIDE) // 7424 ush = 14848 B per head
#define LDS_USH   (XS_SIZE + 8 * WREG_SIZE)  // 76288 ush = 152576 B

__device__ __forceinline__ ushort f2bf(float f) {
    unsigned u = __float_as_uint(f);
    u += 0x7FFFu + ((u >> 16) & 1u);   // RNE
    return (ushort)(u >> 16);
}
__device__ __forceinline__ unsigned pack2(float a, float b) {
    return (unsigned)f2bf(a) | ((unsigned)f2bf(b) << 16);
}

__global__ void lsa_wconv(const float* __restrict__ wqkv,
                          const float* __restrict__ wout,
                          ushort* __restrict__ dst)
{
    int n = blockIdx.x * 256 + threadIdx.x;   // 1024 blocks x 256 = 262144
    float v = (n < 196608) ? wqkv[n] : wout[n - 196608];
    dst[n] = f2bf(v);
}

__global__ __launch_bounds__(1024, 1)
void lsa_fused(const float* __restrict__ x,
               const float* __restrict__ bqkv,
               const float* __restrict__ posb,
               const float* __restrict__ bout,
               const ushort* __restrict__ wqkvb,
               const ushort* __restrict__ woutb,
               float* __restrict__ y)
{
    __shared__ __align__(16) ushort sm[LDS_USH];

    const int t    = threadIdx.x;
    const int wv   = t >> 6;        // 0..15
    const int lane = t & 63;
    const int g    = lane >> 4;     // lane group 0..3
    const int c    = lane & 15;     // lane col 0..15
    const int head = wv >> 1;
    const int half = wv & 1;
    const int bx   = blockIdx.x;
    const int b    = bx / NWIN;
    const int win  = bx - b * NWIN;
    const int wi   = win / NWROW;
    const int wj   = win - wi * NWROW;
    const int hbase = wi * 8 - PADO;
    const int wbase = wj * 8 - PADO;

    // ---------------- phase 0: stage x tile (bf16, [pos][ch]) ----------------
    #pragma unroll 4
    for (int i = 0; i < 16; ++i) {
        int n  = (i << 10) + t;
        int ch = n >> 6;
        int p  = n & 63;
        int h  = hbase + (p >> 3);
        int w  = wbase + (p & 7);
        float v = 0.0f;
        if ((unsigned)h < (unsigned)HIMG && (unsigned)w < (unsigned)HIMG)
            v = x[(((size_t)b * CIN + ch) * HIMG + h) * HIMG + w];
        sm[p * XS_STRIDE + ch] = f2bf(v);
    }
    __syncthreads();

    ushort* hreg = &sm[XS_SIZE + head * WREG_SIZE];

    // ---------------- phase 1: QKV GEMM (wave = head x pos-half) ----------------
    // m-tiles: s6 = sect*2 + mt, sect 0=q 1=k 2=v; m0 = sect*256 + head*32 + mt*16
    f32x4 acc[6][2];
    #pragma unroll
    for (int i = 0; i < 6; ++i)
        #pragma unroll
        for (int j = 0; j < 2; ++j)
            acc[i][j] = (f32x4){0.f, 0.f, 0.f, 0.f};

    const ushort* wrow[6];
    #pragma unroll
    for (int s6 = 0; s6 < 6; ++s6) {
        int m0 = (s6 >> 1) * 256 + head * 32 + (s6 & 1) * 16;
        wrow[s6] = wqkvb + (size_t)(m0 + c) * CIN;
    }

    #pragma unroll
    for (int ks = 0; ks < 8; ++ks) {
        bf16x8 bfr[2];
        #pragma unroll
        for (int p = 0; p < 2; ++p) {
            const int pt = half * 2 + p;
            bfr[p] = *(const bf16x8*)&sm[(pt * 16 + c) * XS_STRIDE + ks * 32 + 8 * g];
        }
        #pragma unroll
        for (int s6 = 0; s6 < 6; ++s6) {
            bf16x8 afr = *(const bf16x8*)(wrow[s6] + ks * 32 + 8 * g);
            #pragma unroll
            for (int p = 0; p < 2; ++p)
                acc[s6][p] = __builtin_amdgcn_mfma_f32_16x16x32_bf16(afr, bfr[p], acc[s6][p], 0, 0, 0);
        }
    }

    // epilogue: bias (+posbias, scale for q) -> head LDS q/k/vT
    #pragma unroll
    for (int s6 = 0; s6 < 6; ++s6) {
        const int sect = s6 >> 1;
        const int mt   = s6 & 1;
        const int m0   = sect * 256 + head * 32 + mt * 16;
        f32x4 bq = *(const f32x4*)&bqkv[m0 + 4 * g];
        #pragma unroll
        for (int p = 0; p < 2; ++p) {
            const int pos = (half * 2 + p) * 16 + c;
            f32x4 a = acc[s6][p];
            if (sect == 0) {
                float v0 = (a[0] + bq[0] + posb[(m0 + 4 * g + 0) * 64 + pos]) * ATT_SCALE;
                float v1 = (a[1] + bq[1] + posb[(m0 + 4 * g + 1) * 64 + pos]) * ATT_SCALE;
                float v2 = (a[2] + bq[2] + posb[(m0 + 4 * g + 2) * 64 + pos]) * ATT_SCALE;
                float v3 = (a[3] + bq[3] + posb[(m0 + 4 * g + 3) * 64 + pos]) * ATT_SCALE;
                unsigned w01 = pack2(v0, v1), w23 = pack2(v2, v3);
                *(unsigned*)&hreg[WREG_Q + pos * QK_STRIDE + mt * 16 + 4 * g]     = w01;
                *(unsigned*)&hreg[WREG_Q + pos * QK_STRIDE + mt * 16 + 4 * g + 2] = w23;
            } else if (sect == 1) {
                unsigned w01 = pack2(a[0] + bq[0], a[1] + bq[1]);
                unsigned w23 = pack2(a[2] + bq[2], a[3] + bq[3]);
                *(unsigned*)&hreg[WREG_K + pos * QK_STRIDE + mt * 16 + 4 * g]     = w01;
                *(unsigned*)&hreg[WREG_K + pos * QK_STRIDE + mt * 16 + 4 * g + 2] = w23;
            } else {
                #pragma unroll
                for (int r = 0; r < 4; ++r)
                    hreg[WREG_VT + (mt * 16 + 4 * g + r) * VT_STRIDE + pos] = f2bf(a[r] + bq[r]);
            }
        }
    }
    __syncthreads();   // head regions complete; all waves done reading xs

    // ---------------- phase 2: attention (wave = head x query-half) ----------------
    bf16x8 kf[4], qf[2];
    #pragma unroll
    for (int kt = 0; kt < 4; ++kt)
        kf[kt] = *(const bf16x8*)&hreg[WREG_K + (kt * 16 + c) * QK_STRIDE + 8 * g];
    #pragma unroll
    for (int q = 0; q < 2; ++q) {
        const int qt = half * 2 + q;
        qf[q] = *(const bf16x8*)&hreg[WREG_Q + (qt * 16 + c) * QK_STRIDE + 8 * g];
    }

    f32x4 s[4][2];   // [kt][q]: D rows = key (kt*16+4g+r), col = query (qt*16+c)
    #pragma unroll
    for (int kt = 0; kt < 4; ++kt)
        #pragma unroll
        for (int q = 0; q < 2; ++q)
            s[kt][q] = __builtin_amdgcn_mfma_f32_16x16x32_bf16(kf[kt], qf[q],
                                                               (f32x4){0.f, 0.f, 0.f, 0.f}, 0, 0, 0);

    float rsum[2];
    #pragma unroll
    for (int q = 0; q < 2; ++q) {
        const int qt = half * 2 + q;
        float mx = s[0][q][0];
        #pragma unroll
        for (int kt = 0; kt < 4; ++kt)
            #pragma unroll
            for (int r = 0; r < 4; ++r)
                mx = fmaxf(mx, s[kt][q][r]);
        mx = fmaxf(mx, __shfl_xor(mx, 16));
        mx = fmaxf(mx, __shfl_xor(mx, 32));
        float sum = 0.f;
        float e[4][4];
        #pragma unroll
        for (int kt = 0; kt < 4; ++kt)
            #pragma unroll
            for (int r = 0; r < 4; ++r) {
                e[kt][r] = __expf(s[kt][q][r] - mx);
                sum += e[kt][r];
            }
        sum += __shfl_xor(sum, 16);
        sum += __shfl_xor(sum, 32);
        rsum[q] = 1.0f / sum;
        // write P row (q = qt*16+c), keys kt*16+4g+0..3  (overlays q/k region)
        #pragma unroll
        for (int kt = 0; kt < 4; ++kt) {
            unsigned w01 = pack2(e[kt][0], e[kt][1]);
            unsigned w23 = pack2(e[kt][2], e[kt][3]);
            *(unsigned*)&hreg[(qt * 16 + c) * P_STRIDE + kt * 16 + 4 * g]     = w01;
            *(unsigned*)&hreg[(qt * 16 + c) * P_STRIDE + kt * 16 + 4 * g + 2] = w23;
        }
    }

    // PV: O^T[d][q] = vT x P   (vT from both halves; P rows are wave-own)
    bf16x8 vf[2][2], pf[2][2];
    #pragma unroll
    for (int dt = 0; dt < 2; ++dt)
        #pragma unroll
        for (int k2 = 0; k2 < 2; ++k2)
            vf[dt][k2] = *(const bf16x8*)&hreg[WREG_VT + (dt * 16 + c) * VT_STRIDE + k2 * 32 + 8 * g];
    #pragma unroll
    for (int q = 0; q < 2; ++q) {
        const int qt = half * 2 + q;
        #pragma unroll
        for (int k2 = 0; k2 < 2; ++k2)
            pf[q][k2] = *(const bf16x8*)&hreg[(qt * 16 + c) * P_STRIDE + k2 * 32 + 8 * g];
    }

    f32x4 o[2][2];
    #pragma unroll
    for (int dt = 0; dt < 2; ++dt)
        #pragma unroll
        for (int q = 0; q < 2; ++q)
            o[dt][q] = (f32x4){0.f, 0.f, 0.f, 0.f};
    #pragma unroll
    for (int k2 = 0; k2 < 2; ++k2)
        #pragma unroll
        for (int dt = 0; dt < 2; ++dt)
            #pragma unroll
            for (int q = 0; q < 2; ++q)
                o[dt][q] = __builtin_amdgcn_mfma_f32_16x16x32_bf16(vf[dt][k2], pf[q][k2], o[dt][q], 0, 0, 0);

    // normalize + write o -> os[pos][ch] (overlays xs)
    #pragma unroll
    for (int dt = 0; dt < 2; ++dt)
        #pragma unroll
        for (int q = 0; q < 2; ++q) {
            const int pos = (half * 2 + q) * 16 + c;
            const int ch0 = head * 32 + dt * 16 + 4 * g;
            float rv = rsum[q];
            unsigned w01 = pack2(o[dt][q][0] * rv, o[dt][q][1] * rv);
            unsigned w23 = pack2(o[dt][q][2] * rv, o[dt][q][3] * rv);
            *(unsigned*)&sm[pos * XS_STRIDE + ch0]     = w01;
            *(unsigned*)&sm[pos * XS_STRIDE + ch0 + 2] = w23;
        }
    __syncthreads();   // os complete

    // ---------------- phase 3: out projection (wave = 16 out channels) ----------------
    f32x4 ya[4];
    #pragma unroll
    for (int j = 0; j < 4; ++j)
        ya[j] = (f32x4){0.f, 0.f, 0.f, 0.f};

    const ushort* worow = woutb + (size_t)(wv * 16 + c) * 256;

    #pragma unroll
    for (int ks = 0; ks < 8; ++ks) {
        bf16x8 afr = *(const bf16x8*)(worow + ks * 32 + 8 * g);
        #pragma unroll
        for (int pt = 0; pt < 4; ++pt) {
            bf16x8 ofr = *(const bf16x8*)&sm[(pt * 16 + c) * XS_STRIDE + ks * 32 + 8 * g];
            ya[pt] = __builtin_amdgcn_mfma_f32_16x16x32_bf16(afr, ofr, ya[pt], 0, 0, 0);
        }
    }

    // epilogue: bias + crop + store (wave owns channels wv*16 .. wv*16+15)
    {
        const int co0 = wv * 16 + 4 * g;
        f32x4 bo = *(const f32x4*)&bout[co0];
        #pragma unroll
        for (int pt = 0; pt < 4; ++pt) {
            const int pos = pt * 16 + c;
            const int hh = wi * 8 + (pos >> 3) - PADO;
            const int ww = wj * 8 + (pos & 7) - PADO;
            if ((unsigned)hh < (unsigned)HIMG && (unsigned)ww < (unsigned)HIMG) {
                #pragma unroll
                for (int r = 0; r < 4; ++r)
                    y[(((size_t)b * 256 + co0 + r) * HIMG + hh) * HIMG + ww] = ya[pt][r] + bo[r];
            }
        }
    }
}

extern "C" void kernel_launch(void* const* d_in, const int* in_sizes, int n_in,
                              void* d_out, int out_size, void* d_ws, size_t ws_size,
                              hipStream_t stream)
{
    const float* x    = (const float*)d_in[0];
    const float* wqkv = (const float*)d_in[1];
    const float* bqkv = (const float*)d_in[2];
    const float* posb = (const float*)d_in[3];
    const float* wout = (const float*)d_in[4];
    const float* bout = (const float*)d_in[5];
    float* y = (float*)d_out;

    ushort* wqkvb = (ushort*)d_ws;            // 196608 bf16
    ushort* woutb = wqkvb + 196608;           // 65536 bf16  (total 512 KB of ws)

    lsa_wconv<<<dim3(1024), dim3(256), 0, stream>>>(wqkv, wout, wqkvb);
    lsa_fused<<<dim3(4 * NWIN), dim3(1024), 0, stream>>>(x, bqkv, posb, bout, wqkvb, woutb, y);
}

// Round 4
// 202.266 us; speedup vs baseline: 1.1678x; 1.1678x over previous
//
#include <hip/hip_runtime.h>

// LocalSelfAttention2d fused MFMA, R4: 2 blocks/CU.
// B=4, CIN=HC=256, heads=8, dh=32, P=8, img 128x128, pad 4/4 -> 136x136, 17x17 windows.
//
// Block = (b,win), 512 thr (8 waves). Heads processed in 4 groups of 2
// (wave = (head-in-group hw, subwave sw)). Out-proj accumulates in registers
// across groups. LDS 72.7 KB -> 2 blocks/CU. VGPR cap 128 (launch_bounds(512,4)).

typedef __attribute__((ext_vector_type(8))) short bf16x8;
typedef __attribute__((ext_vector_type(4))) float f32x4;

#define NWROW 17
#define NWIN  289
#define ATT_SCALE 0.17677669529663687f  // 1/sqrt(32)

// LDS geometry (ushort units)
#define XS_STRIDE 264                        // 528B rows; frag-read bank classes exactly 8 -> floor
#define XS_SIZE   (64 * XS_STRIDE)           // 16896 ush = 33792 B (ys overlays: 128x66 f32 = 33792 B)
#define QK_STRIDE 40                         // 80B rows
#define VT_STRIDE 72                         // 144B rows
#define OS_STRIDE 72
#define HREG_SIZE (64*QK_STRIDE*2 + 32*VT_STRIDE)   // Q + K + VT = 7424 ush
#define HREG_BASE XS_SIZE
#define OS_BASE   (XS_SIZE + 2*HREG_SIZE)    // 31744
#define LDS_USH   (OS_BASE + 64*OS_STRIDE)   // 36352 ush = 72704 B

__device__ __forceinline__ ushort f2bf(float f) {
    unsigned u = __float_as_uint(f);
    u += 0x7FFFu + ((u >> 16) & 1u);   // RNE
    return (ushort)(u >> 16);
}
__device__ __forceinline__ unsigned pack2(float a, float b) {
    return (unsigned)f2bf(a) | ((unsigned)f2bf(b) << 16);
}

__global__ void lsa_wconv(const float* __restrict__ wqkv,
                          const float* __restrict__ wout,
                          ushort* __restrict__ dst)
{
    int n = blockIdx.x * 256 + threadIdx.x;   // 1024 blocks x 256 = 262144
    float v = (n < 196608) ? wqkv[n] : wout[n - 196608];
    dst[n] = f2bf(v);
}

__global__ __launch_bounds__(512, 4)
void lsa_fused(const float* __restrict__ x,
               const float* __restrict__ bqkv,
               const float* __restrict__ posb,
               const float* __restrict__ bout,
               const ushort* __restrict__ wqkvb,
               const ushort* __restrict__ woutb,
               float* __restrict__ y)
{
    __shared__ __align__(16) ushort sm[LDS_USH];

    const int t    = threadIdx.x;
    const int wv   = t >> 6;        // 0..7
    const int lane = t & 63;
    const int g    = lane >> 4;     // 0..3
    const int c    = lane & 15;     // 0..15
    const int hw   = wv >> 2;       // head-in-group
    const int sw   = wv & 3;        // subwave
    const int mtrip = sw >> 1;      // weight-row triple
    const int pp2   = sw & 1;       // pos-tile pair

    // bijective XCD chunk swizzle (nwg=1156: q=144,r=4) -> consecutive windows same XCD
    const int orig = blockIdx.x;
    const int xcd  = orig & 7;
    const int idx  = orig >> 3;
    const int bid  = (xcd < 4 ? xcd * 145 : 580 + (xcd - 4) * 144) + idx;

    const int b   = bid / NWIN;
    const int win = bid - b * NWIN;
    const int wi  = win / NWROW;
    const int wj  = win - wi * NWROW;
    const int hbase = wi * 8 - 4;
    const int wbase = wj * 8 - 4;

    // ---------------- phase 0: stage x tile (bf16 [pos][ch]), float4 loads ----------------
    // quads are 4-aligned in w; pad=4 makes each quad fully in or fully out of the image.
    #pragma unroll
    for (int i = 0; i < 8; ++i) {
        int id = (i << 9) + t;
        int ch = id >> 4;
        int qd = id & 15;           // window quad: hh = qd>>1, wq = qd&1
        int h  = hbase + (qd >> 1);
        int w0 = wbase + (qd & 1) * 4;
        f32x4 v = (f32x4){0.f, 0.f, 0.f, 0.f};
        if ((unsigned)h < 128u && (unsigned)w0 < 125u)
            v = *(const f32x4*)&x[(((size_t)b * 256 + ch) * 128 + h) * 128 + w0];
        ushort bs[4] = {f2bf(v[0]), f2bf(v[1]), f2bf(v[2]), f2bf(v[3])};
        #pragma unroll
        for (int e = 0; e < 4; ++e) {        // qd-swizzled order spreads LDS banks
            int ee = (e + qd) & 3;
            sm[(qd * 4 + ee) * XS_STRIDE + ch] = bs[ee];
        }
    }
    __syncthreads();

    f32x4 ya[2][4];                 // persistent out-proj accumulators
    #pragma unroll
    for (int i = 0; i < 2; ++i)
        #pragma unroll
        for (int j = 0; j < 4; ++j)
            ya[i][j] = (f32x4){0.f, 0.f, 0.f, 0.f};

    ushort* hreg = &sm[HREG_BASE + hw * HREG_SIZE];   // Q[0..2560) K[2560..5120) VT[5120..7424)

    for (int hg = 0; hg < 4; ++hg) {
        const int head = hg * 2 + hw;

        // ---------------- phase 1: QKV GEMM for this head ----------------
        // wave covers mtiles {mtrip*3..+2} x ptiles {pp2*2, pp2*2+1}, K=256
        f32x4 acc[3][2];
        #pragma unroll
        for (int i = 0; i < 3; ++i)
            #pragma unroll
            for (int j = 0; j < 2; ++j)
                acc[i][j] = (f32x4){0.f, 0.f, 0.f, 0.f};

        const ushort* wr[3];
        #pragma unroll
        for (int j = 0; j < 3; ++j) {
            int s6 = mtrip * 3 + j;
            int m0 = (s6 >> 1) * 256 + head * 32 + (s6 & 1) * 16;
            wr[j] = wqkvb + (size_t)(m0 + c) * 256;
        }

        #pragma unroll
        for (int ks = 0; ks < 8; ++ks) {
            bf16x8 bfr[2];
            #pragma unroll
            for (int p = 0; p < 2; ++p)
                bfr[p] = *(const bf16x8*)&sm[((pp2 * 2 + p) * 16 + c) * XS_STRIDE + ks * 32 + 8 * g];
            #pragma unroll
            for (int j = 0; j < 3; ++j) {
                bf16x8 afr = *(const bf16x8*)(wr[j] + ks * 32 + 8 * g);
                #pragma unroll
                for (int p = 0; p < 2; ++p)
                    acc[j][p] = __builtin_amdgcn_mfma_f32_16x16x32_bf16(afr, bfr[p], acc[j][p], 0, 0, 0);
            }
        }

        // epilogue -> head LDS q/k/vT
        #pragma unroll
        for (int j = 0; j < 3; ++j) {
            const int s6   = mtrip * 3 + j;
            const int sect = s6 >> 1;
            const int mt   = s6 & 1;
            const int m0q  = head * 32 + mt * 16;          // q/k/v-local channel base
            f32x4 bq = *(const f32x4*)&bqkv[sect * 256 + m0q + 4 * g];
            #pragma unroll
            for (int p = 0; p < 2; ++p) {
                const int pos = (pp2 * 2 + p) * 16 + c;
                f32x4 a = acc[j][p];
                if (sect == 0) {
                    float v0 = (a[0] + bq[0] + posb[(m0q + 4*g + 0) * 64 + pos]) * ATT_SCALE;
                    float v1 = (a[1] + bq[1] + posb[(m0q + 4*g + 1) * 64 + pos]) * ATT_SCALE;
                    float v2 = (a[2] + bq[2] + posb[(m0q + 4*g + 2) * 64 + pos]) * ATT_SCALE;
                    float v3 = (a[3] + bq[3] + posb[(m0q + 4*g + 3) * 64 + pos]) * ATT_SCALE;
                    *(unsigned*)&hreg[pos * QK_STRIDE + mt * 16 + 4 * g]     = pack2(v0, v1);
                    *(unsigned*)&hreg[pos * QK_STRIDE + mt * 16 + 4 * g + 2] = pack2(v2, v3);
                } else if (sect == 1) {
                    *(unsigned*)&hreg[2560 + pos * QK_STRIDE + mt * 16 + 4 * g]     = pack2(a[0] + bq[0], a[1] + bq[1]);
                    *(unsigned*)&hreg[2560 + pos * QK_STRIDE + mt * 16 + 4 * g + 2] = pack2(a[2] + bq[2], a[3] + bq[3]);
                } else {
                    #pragma unroll
                    for (int r = 0; r < 4; ++r)
                        hreg[5120 + (mt * 16 + 4 * g + r) * VT_STRIDE + pos] = f2bf(a[r] + bq[r]);
                }
            }
        }
        __syncthreads();   // B1: q/k/vT visible

        // ---------------- phase 2: attention (wave owns queries sw*16..+15) ----------------
        bf16x8 kf[4], vf[2][2];
        #pragma unroll
        for (int kt = 0; kt < 4; ++kt)
            kf[kt] = *(const bf16x8*)&hreg[2560 + (kt * 16 + c) * QK_STRIDE + 8 * g];
        bf16x8 qfv = *(const bf16x8*)&hreg[(sw * 16 + c) * QK_STRIDE + 8 * g];
        #pragma unroll
        for (int dt = 0; dt < 2; ++dt)
            #pragma unroll
            for (int k2 = 0; k2 < 2; ++k2)
                vf[dt][k2] = *(const bf16x8*)&hreg[5120 + (dt * 16 + c) * VT_STRIDE + k2 * 32 + 8 * g];

        f32x4 s4[4];   // [kt]: rows key kt*16+4g+r, col query sw*16+c
        #pragma unroll
        for (int kt = 0; kt < 4; ++kt)
            s4[kt] = __builtin_amdgcn_mfma_f32_16x16x32_bf16(kf[kt], qfv,
                                                             (f32x4){0.f,0.f,0.f,0.f}, 0, 0, 0);
        __syncthreads();   // B2: all Q/K reads done before P overlays Q/K slots

        float mx = s4[0][0];
        #pragma unroll
        for (int kt = 0; kt < 4; ++kt)
            #pragma unroll
            for (int r = 0; r < 4; ++r)
                mx = fmaxf(mx, s4[kt][r]);
        mx = fmaxf(mx, __shfl_xor(mx, 16));
        mx = fmaxf(mx, __shfl_xor(mx, 32));
        float sum = 0.f;
        #pragma unroll
        for (int kt = 0; kt < 4; ++kt)
            #pragma unroll
            for (int r = 0; r < 4; ++r) {
                s4[kt][r] = __expf(s4[kt][r] - mx);
                sum += s4[kt][r];
            }
        sum += __shfl_xor(sum, 16);
        sum += __shfl_xor(sum, 32);
        const float rinv = 1.0f / sum;

        // P halves overlay Q (keys 0..31) and K (keys 32..63) row-slots, stride 40
        #pragma unroll
        for (int kt = 0; kt < 4; ++kt) {
            const int base = (kt >> 1) ? 2560 : 0;
            const int lk   = (kt & 1) * 16 + 4 * g;
            *(unsigned*)&hreg[base + (sw * 16 + c) * QK_STRIDE + lk]     = pack2(s4[kt][0], s4[kt][1]);
            *(unsigned*)&hreg[base + (sw * 16 + c) * QK_STRIDE + lk + 2] = pack2(s4[kt][2], s4[kt][3]);
        }

        bf16x8 pf[2];
        #pragma unroll
        for (int k2 = 0; k2 < 2; ++k2)
            pf[k2] = *(const bf16x8*)&hreg[(k2 ? 2560 : 0) + (sw * 16 + c) * QK_STRIDE + 8 * g];

        f32x4 o2[2];
        o2[0] = (f32x4){0.f,0.f,0.f,0.f};
        o2[1] = (f32x4){0.f,0.f,0.f,0.f};
        #pragma unroll
        for (int k2 = 0; k2 < 2; ++k2)
            #pragma unroll
            for (int dt = 0; dt < 2; ++dt)
                o2[dt] = __builtin_amdgcn_mfma_f32_16x16x32_bf16(vf[dt][k2], pf[k2], o2[dt], 0, 0, 0);

        // o -> os[pos][group-local ch]
        #pragma unroll
        for (int dt = 0; dt < 2; ++dt) {
            const int chl = hw * 32 + dt * 16 + 4 * g;
            const int pos = sw * 16 + c;
            *(unsigned*)&sm[OS_BASE + pos * OS_STRIDE + chl]     = pack2(o2[dt][0]*rinv, o2[dt][1]*rinv);
            *(unsigned*)&sm[OS_BASE + pos * OS_STRIDE + chl + 2] = pack2(o2[dt][2]*rinv, o2[dt][3]*rinv);
        }
        __syncthreads();   // B3: os visible

        // ---------------- phase 3 partial: out-proj k-steps for this group ----------------
        #pragma unroll
        for (int ksl = 0; ksl < 2; ++ksl) {
            bf16x8 ofr[4];
            #pragma unroll
            for (int pt = 0; pt < 4; ++pt)
                ofr[pt] = *(const bf16x8*)&sm[OS_BASE + (pt * 16 + c) * OS_STRIDE + ksl * 32 + 8 * g];
            #pragma unroll
            for (int mt = 0; mt < 2; ++mt) {
                bf16x8 afr = *(const bf16x8*)(woutb + (size_t)((wv * 2 + mt) * 16 + c) * 256
                                              + hg * 64 + ksl * 32 + 8 * g);
                #pragma unroll
                for (int pt = 0; pt < 4; ++pt)
                    ya[mt][pt] = __builtin_amdgcn_mfma_f32_16x16x32_bf16(afr, ofr[pt], ya[mt][pt], 0, 0, 0);
            }
        }
        // no barrier: next group's first shared-LDS write (epilogue) is ordered by its B1
    }

    // ---------------- epilogue: in-wave LDS transpose -> float4 y stores ----------------
    // ys overlays xs (dead). Rows are wave-private (write own 16, read own 16): no barriers.
    float* ys = (float*)sm;           // [128][66] f32 per pass
    #pragma unroll
    for (int mt = 0; mt < 2; ++mt) {
        f32x4 bo = *(const f32x4*)&bout[(wv * 2 + mt) * 16 + 4 * g];
        #pragma unroll
        for (int pt = 0; pt < 4; ++pt) {
            const int pos = pt * 16 + c;
            #pragma unroll
            for (int r = 0; r < 4; ++r)
                ys[(wv * 16 + 4 * g + r) * 66 + pos] = ya[mt][pt][r] + bo[r];
        }
        // read back own rows as 8-float row chunks, store float4 pairs with crop
        #pragma unroll
        for (int k = 0; k < 2; ++k) {
            const int col = wv * 16 + k * 8 + (lane >> 3);   // co_local
            const int hh  = lane & 7;
            float2 p0 = *(float2*)&ys[col * 66 + hh * 8];
            float2 p1 = *(float2*)&ys[col * 66 + hh * 8 + 2];
            float2 p2 = *(float2*)&ys[col * 66 + hh * 8 + 4];
            float2 p3 = *(float2*)&ys[col * 66 + hh * 8 + 6];
            const int co  = ((col >> 4) * 2 + mt) * 16 + (col & 15);
            const int him = wi * 8 + hh - 4;
            if ((unsigned)him < 128u) {
                float* yrow = y + (((size_t)b * 256 + co) * 128 + him) * 128;
                if (wj > 0)  { f32x4 v0 = {p0.x, p0.y, p1.x, p1.y}; *(f32x4*)&yrow[wbase]     = v0; }
                if (wj < 16) { f32x4 v1 = {p2.x, p2.y, p3.x, p3.y}; *(f32x4*)&yrow[wbase + 4] = v1; }
            }
        }
        if (mt == 0) __syncthreads();   // reuse ys rows for pass 1 (same rows, but cheap safety)
    }
}

extern "C" void kernel_launch(void* const* d_in, const int* in_sizes, int n_in,
                              void* d_out, int out_size, void* d_ws, size_t ws_size,
                              hipStream_t stream)
{
    const float* x    = (const float*)d_in[0];
    const float* wqkv = (const float*)d_in[1];
    const float* bqkv = (const float*)d_in[2];
    const float* posb = (const float*)d_in[3];
    const float* wout = (const float*)d_in[4];
    const float* bout = (const float*)d_in[5];
    float* y = (float*)d_out;

    ushort* wqkvb = (ushort*)d_ws;            // 196608 bf16
    ushort* woutb = wqkvb + 196608;           // 65536 bf16

    lsa_wconv<<<dim3(1024), dim3(256), 0, stream>>>(wqkv, wout, wqkvb);
    lsa_fused<<<dim3(4 * NWIN), dim3(512), 0, stream>>>(x, bqkv, posb, bout, wqkvb, woutb, y);
}

// Round 6
// 126.397 us; speedup vs baseline: 1.8688x; 1.6002x over previous
//
#include <hip/hip_runtime.h>

// LocalSelfAttention2d fused MFMA, R6: wave-private dataflow, 4 barriers,
// FIXED injective LDS layouts (R5 had stride-40 rows of length 64 -> corruption).
// B=4, CIN=HC=256, heads=8, dh=32, P=8, img 128x128, pad 4/4 -> 136x136, 17x17 win.
//
// Block = (b,win), 512 thr, wave = head. Per-wave 2560-ush private slice reused
// in sequential generations (same-wave RAW via in-order DS pipe, no barriers):
//   Qt[64x32 s40] -> qf -> Kt[64x32 s40] -> kf -> VT[32x64 s72] -> vf
//   -> P0[64x32 s40](keys 0..31) -> pf0 -> P1[same](keys 32..63) -> pf1
// Barriers: B0 x staged; B1 xs dead (os overlays); B2 os ready; B3 os dead (ys).

typedef __attribute__((ext_vector_type(8))) short bf16x8;
typedef __attribute__((ext_vector_type(4))) float f32x4;

#define NWROW 17
#define NWIN  289
#define ATT_SCALE 0.17677669529663687f  // 1/sqrt(32)

// LDS geometry (ushort units)
#define XS_STRIDE 264                    // 528B rows (16B aligned)
#define XS_SIZE   (64 * XS_STRIDE)       // 16896 ush = 33792 B (os, ys overlay this)
#define WPRIV     2560                   // per-wave private scratch
#define LDS_USH   (XS_SIZE + 8 * WPRIV)  // 37376 ush = 74752 B -> 2 blocks/CU

__device__ __forceinline__ ushort f2bf(float f) {
    unsigned u = __float_as_uint(f);
    u += 0x7FFFu + ((u >> 16) & 1u);   // RNE
    return (ushort)(u >> 16);
}
__device__ __forceinline__ unsigned pack2(float a, float b) {
    return (unsigned)f2bf(a) | ((unsigned)f2bf(b) << 16);
}

__global__ void lsa_wconv(const float* __restrict__ wqkv,
                          const float* __restrict__ wout,
                          ushort* __restrict__ dst)
{
    int n = blockIdx.x * 256 + threadIdx.x;   // 1024 x 256 = 262144
    float v = (n < 196608) ? wqkv[n] : wout[n - 196608];
    dst[n] = f2bf(v);
}

__global__ __launch_bounds__(512, 4)
void lsa_fused(const float* __restrict__ x,
               const float* __restrict__ bqkv,
               const float* __restrict__ posb,
               const float* __restrict__ bout,
               const ushort* __restrict__ wqkvb,
               const ushort* __restrict__ woutb,
               float* __restrict__ y)
{
    __shared__ __align__(16) ushort sm[LDS_USH];

    const int t    = threadIdx.x;
    const int wv   = t >> 6;        // wave = head
    const int lane = t & 63;
    const int g    = lane >> 4;     // 0..3
    const int c    = lane & 15;     // 0..15
    const int head = wv;

    // bijective XCD chunk swizzle (nwg=1156: q=144, r=4)
    const int orig = blockIdx.x;
    const int xcd  = orig & 7;
    const int idx  = orig >> 3;
    const int bid  = (xcd < 4 ? xcd * 145 : 580 + (xcd - 4) * 144) + idx;

    const int b   = bid / NWIN;
    const int win = bid - b * NWIN;
    const int wi  = win / NWROW;
    const int wj  = win - wi * NWROW;
    const int hbase = wi * 8 - 4;
    const int wbase = wj * 8 - 4;

    // ---------------- phase 0: stage x tile (bf16 [pos][ch]) ----------------
    #pragma unroll
    for (int i = 0; i < 8; ++i) {
        int id = (i << 9) + t;
        int ch = id >> 4;
        int qd = id & 15;           // hh = qd>>1, wquad = qd&1
        int h  = hbase + (qd >> 1);
        int w0 = wbase + (qd & 1) * 4;
        f32x4 v = (f32x4){0.f, 0.f, 0.f, 0.f};
        if ((unsigned)h < 128u && (unsigned)w0 < 125u)
            v = *(const f32x4*)&x[(((size_t)b * 256 + ch) * 128 + h) * 128 + w0];
        ushort bs[4] = {f2bf(v[0]), f2bf(v[1]), f2bf(v[2]), f2bf(v[3])};
        #pragma unroll
        for (int e = 0; e < 4; ++e) {
            int ee = (e + qd) & 3;
            sm[(qd * 4 + ee) * XS_STRIDE + ch] = bs[ee];
        }
    }
    __syncthreads();   // B0

    ushort* priv = &sm[XS_SIZE + wv * WPRIV];

    // ---------------- pass A: q,k projection (4 m-tiles x 4 p-tiles) ----------------
    f32x4 acc[4][4];
    #pragma unroll
    for (int i = 0; i < 4; ++i)
        #pragma unroll
        for (int j = 0; j < 4; ++j)
            acc[i][j] = (f32x4){0.f, 0.f, 0.f, 0.f};

    const ushort* wr[4];
    #pragma unroll
    for (int j = 0; j < 4; ++j) {
        int m0 = (j >> 1) * 256 + head * 32 + (j & 1) * 16;   // sect 0=q,1=k
        wr[j] = wqkvb + (size_t)(m0 + c) * 256;
    }

    #pragma unroll
    for (int ks = 0; ks < 8; ++ks) {
        bf16x8 bfr[4];
        #pragma unroll
        for (int pt = 0; pt < 4; ++pt)
            bfr[pt] = *(const bf16x8*)&sm[(pt * 16 + c) * XS_STRIDE + ks * 32 + 8 * g];
        #pragma unroll
        for (int j = 0; j < 4; ++j) {
            bf16x8 afr = *(const bf16x8*)(wr[j] + ks * 32 + 8 * g);
            #pragma unroll
            for (int pt = 0; pt < 4; ++pt)
                acc[j][pt] = __builtin_amdgcn_mfma_f32_16x16x32_bf16(afr, bfr[pt], acc[j][pt], 0, 0, 0);
        }
    }

    // q epilogue -> Qt[pos][32d] stride 40 (injective: row len 32 <= 40)
    #pragma unroll
    for (int mt = 0; mt < 2; ++mt) {
        f32x4 bq = *(const f32x4*)&bqkv[head * 32 + mt * 16 + 4 * g];
        #pragma unroll
        for (int pt = 0; pt < 4; ++pt) {
            const int pos = pt * 16 + c;
            const float* pb = posb + (size_t)(head * 32 + mt * 16 + 4 * g) * 64 + pos;
            float v0 = (acc[mt][pt][0] + bq[0] + pb[0])   * ATT_SCALE;
            float v1 = (acc[mt][pt][1] + bq[1] + pb[64])  * ATT_SCALE;
            float v2 = (acc[mt][pt][2] + bq[2] + pb[128]) * ATT_SCALE;
            float v3 = (acc[mt][pt][3] + bq[3] + pb[192]) * ATT_SCALE;
            *(unsigned*)&priv[pos * 40 + mt * 16 + 4 * g]     = pack2(v0, v1);
            *(unsigned*)&priv[pos * 40 + mt * 16 + 4 * g + 2] = pack2(v2, v3);
        }
    }
    bf16x8 qf[4];
    #pragma unroll
    for (int qt = 0; qt < 4; ++qt)
        qf[qt] = *(const bf16x8*)&priv[(qt * 16 + c) * 40 + 8 * g];

    // k epilogue -> Kt (same slots; same-wave RAW through in-order DS pipe)
    #pragma unroll
    for (int mt = 0; mt < 2; ++mt) {
        f32x4 bk = *(const f32x4*)&bqkv[256 + head * 32 + mt * 16 + 4 * g];
        #pragma unroll
        for (int pt = 0; pt < 4; ++pt) {
            const int pos = pt * 16 + c;
            *(unsigned*)&priv[pos * 40 + mt * 16 + 4 * g]     = pack2(acc[mt + 2][pt][0] + bk[0], acc[mt + 2][pt][1] + bk[1]);
            *(unsigned*)&priv[pos * 40 + mt * 16 + 4 * g + 2] = pack2(acc[mt + 2][pt][2] + bk[2], acc[mt + 2][pt][3] + bk[3]);
        }
    }
    bf16x8 kf[4];
    #pragma unroll
    for (int kt = 0; kt < 4; ++kt)
        kf[kt] = *(const bf16x8*)&priv[(kt * 16 + c) * 40 + 8 * g];

    // ---------------- pass B: v projection (2 m-tiles x 4 p-tiles) ----------------
    f32x4 av[2][4];
    #pragma unroll
    for (int i = 0; i < 2; ++i)
        #pragma unroll
        for (int j = 0; j < 4; ++j)
            av[i][j] = (f32x4){0.f, 0.f, 0.f, 0.f};
    const ushort* wv0 = wqkvb + (size_t)(512 + head * 32 + c) * 256;
    const ushort* wv1 = wqkvb + (size_t)(512 + head * 32 + 16 + c) * 256;

    #pragma unroll
    for (int ks = 0; ks < 8; ++ks) {
        bf16x8 bfr[4];
        #pragma unroll
        for (int pt = 0; pt < 4; ++pt)
            bfr[pt] = *(const bf16x8*)&sm[(pt * 16 + c) * XS_STRIDE + ks * 32 + 8 * g];
        bf16x8 a0 = *(const bf16x8*)(wv0 + ks * 32 + 8 * g);
        bf16x8 a1 = *(const bf16x8*)(wv1 + ks * 32 + 8 * g);
        #pragma unroll
        for (int pt = 0; pt < 4; ++pt) {
            av[0][pt] = __builtin_amdgcn_mfma_f32_16x16x32_bf16(a0, bfr[pt], av[0][pt], 0, 0, 0);
            av[1][pt] = __builtin_amdgcn_mfma_f32_16x16x32_bf16(a1, bfr[pt], av[1][pt], 0, 0, 0);
        }
    }

    // v epilogue -> VT[32 d][64 pos] STRIDE 72 (injective: 64 <= 72; 32*72=2304 <= 2560)
    // overwrites Qt/Kt rows; qf/kf already in regs.
    #pragma unroll
    for (int mt = 0; mt < 2; ++mt) {
        f32x4 bv = *(const f32x4*)&bqkv[512 + head * 32 + mt * 16 + 4 * g];
        #pragma unroll
        for (int pt = 0; pt < 4; ++pt) {
            #pragma unroll
            for (int r = 0; r < 4; ++r)
                priv[(mt * 16 + 4 * g + r) * 72 + pt * 16 + c] = f2bf(av[mt][pt][r] + bv[r]);
        }
    }

    // ---------------- attention (fully wave-private, no barriers) ----------------
    f32x4 s[4][4];   // [kt][qt]: D row = key kt*16+4g+r, col = query qt*16+c
    #pragma unroll
    for (int kt = 0; kt < 4; ++kt)
        #pragma unroll
        for (int qt = 0; qt < 4; ++qt)
            s[kt][qt] = __builtin_amdgcn_mfma_f32_16x16x32_bf16(kf[kt], qf[qt],
                                                                (f32x4){0.f,0.f,0.f,0.f}, 0, 0, 0);

    float rinv[4];
    #pragma unroll
    for (int qt = 0; qt < 4; ++qt) {
        float mx = s[0][qt][0];
        #pragma unroll
        for (int kt = 0; kt < 4; ++kt)
            #pragma unroll
            for (int r = 0; r < 4; ++r)
                mx = fmaxf(mx, s[kt][qt][r]);
        mx = fmaxf(mx, __shfl_xor(mx, 16));
        mx = fmaxf(mx, __shfl_xor(mx, 32));
        float sum = 0.f;
        #pragma unroll
        for (int kt = 0; kt < 4; ++kt)
            #pragma unroll
            for (int r = 0; r < 4; ++r) {
                s[kt][qt][r] = __expf(s[kt][qt][r] - mx);
                sum += s[kt][qt][r];
            }
        sum += __shfl_xor(sum, 16);
        sum += __shfl_xor(sum, 32);
        rinv[qt] = 1.0f / sum;
    }

    // vf BEFORE P overwrites VT
    bf16x8 vf[2][2];
    #pragma unroll
    for (int dt = 0; dt < 2; ++dt)
        #pragma unroll
        for (int k2 = 0; k2 < 2; ++k2)
            vf[dt][k2] = *(const bf16x8*)&priv[(dt * 16 + c) * 72 + k2 * 32 + 8 * g];

    // PV in two sequential key-half generations through the same P slots
    f32x4 o[2][4];
    #pragma unroll
    for (int dt = 0; dt < 2; ++dt)
        #pragma unroll
        for (int qt = 0; qt < 4; ++qt)
            o[dt][qt] = (f32x4){0.f,0.f,0.f,0.f};

    #pragma unroll
    for (int k2 = 0; k2 < 2; ++k2) {
        // write P[q][local key 0..31] stride 40 from s[2*k2], s[2*k2+1]
        #pragma unroll
        for (int qt = 0; qt < 4; ++qt)
            #pragma unroll
            for (int kl = 0; kl < 2; ++kl) {
                const int kt = k2 * 2 + kl;
                *(unsigned*)&priv[(qt * 16 + c) * 40 + kl * 16 + 4 * g]     = pack2(s[kt][qt][0], s[kt][qt][1]);
                *(unsigned*)&priv[(qt * 16 + c) * 40 + kl * 16 + 4 * g + 2] = pack2(s[kt][qt][2], s[kt][qt][3]);
            }
        #pragma unroll
        for (int qt = 0; qt < 4; ++qt) {
            bf16x8 pf = *(const bf16x8*)&priv[(qt * 16 + c) * 40 + 8 * g];
            #pragma unroll
            for (int dt = 0; dt < 2; ++dt)
                o[dt][qt] = __builtin_amdgcn_mfma_f32_16x16x32_bf16(vf[dt][k2], pf, o[dt][qt], 0, 0, 0);
        }
    }

    __syncthreads();   // B1: every wave done reading xs; o may overlay it

    // o -> os[pos][ch] (xs overlay)
    #pragma unroll
    for (int dt = 0; dt < 2; ++dt)
        #pragma unroll
        for (int qt = 0; qt < 4; ++qt) {
            const int pos = qt * 16 + c;
            const int ch0 = head * 32 + dt * 16 + 4 * g;
            float rv = rinv[qt];
            *(unsigned*)&sm[pos * XS_STRIDE + ch0]     = pack2(o[dt][qt][0]*rv, o[dt][qt][1]*rv);
            *(unsigned*)&sm[pos * XS_STRIDE + ch0 + 2] = pack2(o[dt][qt][2]*rv, o[dt][qt][3]*rv);
        }
    __syncthreads();   // B2: os complete

    // ---------------- out projection: wave owns out-ch wv*32..+31, K=256 ----------------
    f32x4 ya[2][4];
    #pragma unroll
    for (int i = 0; i < 2; ++i)
        #pragma unroll
        for (int j = 0; j < 4; ++j)
            ya[i][j] = (f32x4){0.f,0.f,0.f,0.f};

    const ushort* wo0 = woutb + (size_t)(wv * 32 + c) * 256;
    const ushort* wo1 = woutb + (size_t)(wv * 32 + 16 + c) * 256;

    #pragma unroll
    for (int ks = 0; ks < 8; ++ks) {
        bf16x8 ofr[4];
        #pragma unroll
        for (int pt = 0; pt < 4; ++pt)
            ofr[pt] = *(const bf16x8*)&sm[(pt * 16 + c) * XS_STRIDE + ks * 32 + 8 * g];
        bf16x8 a0 = *(const bf16x8*)(wo0 + ks * 32 + 8 * g);
        bf16x8 a1 = *(const bf16x8*)(wo1 + ks * 32 + 8 * g);
        #pragma unroll
        for (int pt = 0; pt < 4; ++pt) {
            ya[0][pt] = __builtin_amdgcn_mfma_f32_16x16x32_bf16(a0, ofr[pt], ya[0][pt], 0, 0, 0);
            ya[1][pt] = __builtin_amdgcn_mfma_f32_16x16x32_bf16(a1, ofr[pt], ya[1][pt], 0, 0, 0);
        }
    }
    __syncthreads();   // B3: os reads done; ys may overlay

    // ---------------- epilogue: per-wave LDS transpose -> float4 y stores ----------------
    float* ys = (float*)sm;           // [128 col][66] f32; rows wave-private
    #pragma unroll
    for (int mt = 0; mt < 2; ++mt) {
        f32x4 bo = *(const f32x4*)&bout[wv * 32 + mt * 16 + 4 * g];
        #pragma unroll
        for (int pt = 0; pt < 4; ++pt) {
            const int pos = pt * 16 + c;
            #pragma unroll
            for (int r = 0; r < 4; ++r)
                ys[(wv * 16 + 4 * g + r) * 66 + pos] = ya[mt][pt][r] + bo[r];
        }
        #pragma unroll
        for (int k = 0; k < 2; ++k) {
            const int col = wv * 16 + k * 8 + (lane >> 3);
            const int hh  = lane & 7;
            float2 p0 = *(float2*)&ys[col * 66 + hh * 8];
            float2 p1 = *(float2*)&ys[col * 66 + hh * 8 + 2];
            float2 p2 = *(float2*)&ys[col * 66 + hh * 8 + 4];
            float2 p3 = *(float2*)&ys[col * 66 + hh * 8 + 6];
            const int co  = ((col >> 4) * 2 + mt) * 16 + (col & 15);
            const int him = wi * 8 + hh - 4;
            if ((unsigned)him < 128u) {
                float* yrow = y + (((size_t)b * 256 + co) * 128 + him) * 128;
                if (wj > 0)  { f32x4 v0 = {p0.x, p0.y, p1.x, p1.y}; *(f32x4*)&yrow[wbase]     = v0; }
                if (wj < 16) { f32x4 v1 = {p2.x, p2.y, p3.x, p3.y}; *(f32x4*)&yrow[wbase + 4] = v1; }
            }
        }
    }
}

extern "C" void kernel_launch(void* const* d_in, const int* in_sizes, int n_in,
                              void* d_out, int out_size, void* d_ws, size_t ws_size,
                              hipStream_t stream)
{
    const float* x    = (const float*)d_in[0];
    const float* wqkv = (const float*)d_in[1];
    const float* bqkv = (const float*)d_in[2];
    const float* posb = (const float*)d_in[3];
    const float* wout = (const float*)d_in[4];
    const float* bout = (const float*)d_in[5];
    float* y = (float*)d_out;

    ushort* wqkvb = (ushort*)d_ws;            // 196608 bf16
    ushort* woutb = wqkvb + 196608;           // 65536 bf16

    lsa_wconv<<<dim3(1024), dim3(256), 0, stream>>>(wqkv, wout, wqkvb);
    lsa_fused<<<dim3(4 * NWIN), dim3(512), 0, stream>>>(x, bqkv, posb, bout, wqkvb, woutb, y);
}